// Round 1
// baseline (943.893 us; speedup 1.0000x reference)
//
#include <hip/hip_runtime.h>

// Features2im: Winograd-style 4x4 inverse coeff transform + 2x2/stride-1
// overlap-add fold onto (H+1,W+1), normalized by fold counts.
//
// GK_inv (exact, derived from GK = diag(0.25,-.5,-.5,-.5) * Hadamard):
//   g00 = f0 -.5f1 -.5f2 -.5f3     (di=0,dj=0)
//   g01 = f0 +.5f1 -.5f2 +.5f3     (di=0,dj=1)
//   g10 = f0 -.5f1 +.5f2 +.5f3     (di=1,dj=0)
//   g11 = f0 +.5f1 +.5f2 -.5f3     (di=1,dj=1)
// out[i,j] = (g00[i,j] + g01[i,j-1] + g10[i-1,j] + g11[i-1,j-1]) / (ci*cj)
// Scan form: U[r,j] = g00[r,j]+g01[r,j-1]; L[r,j] = g10[r,j]+g11[r,j-1];
//            out[i,j] = U[i,j] + L[i-1,j]   (terms dropped out of range)

#define HH 512
#define WW 512
#define OW 513
#define RSTRIP 27   // output rows per block strip; 27*19 = 513
#define NSTRIP 19

__global__ __launch_bounds__(128) void features2im_kernel(
    const float* __restrict__ in0, const float* __restrict__ in1,
    const float* __restrict__ in2, const float* __restrict__ in3,
    float* __restrict__ out)
{
    const int t  = threadIdx.x;        // 0..127, owns output cols 4t..4t+3
    const int j0 = t * 4;
    const int bc = blockIdx.y;         // 0..255 (b*64+c plane)
    const int o0 = blockIdx.x * RSTRIP;

    const int inoff = bc * (HH * WW);
    const float* p0 = in0 + inoff;
    const float* p1 = in1 + inoff;
    const float* p2 = in2 + inoff;
    const float* p3 = in3 + inoff;
    float* po = out + (size_t)bc * (OW * OW);

    const int r_start = (o0 == 0) ? 0 : (o0 - 1);
    const int r_end   = min(o0 + RSTRIP - 1, HH - 1);

    // carried L row (g10/g11 contributions from previous input row)
    float pLx = 0.f, pLy = 0.f, pLz = 0.f, pLw = 0.f;
    float pL512 = 0.f;                 // col-512 carry (thread 127 only)

    const float cj0 = (t == 0) ? 1.0f : 0.5f;   // column-count inverse for col j0

    for (int r = r_start; r <= r_end; ++r) {
        const int ro = r * WW + j0;
        const float4 x0 = *(const float4*)(p0 + ro);
        const float4 x1 = *(const float4*)(p1 + ro);
        const float4 x2 = *(const float4*)(p2 + ro);
        const float4 x3 = *(const float4*)(p3 + ro);

        // left-neighbor column (j0-1): same cache line the prior lane loads -> L1 hit
        float l0 = 0.f, l1 = 0.f, l2 = 0.f, l3 = 0.f;
        if (t > 0) {
            l0 = p0[ro - 1]; l1 = p1[ro - 1]; l2 = p2[ro - 1]; l3 = p3[ro - 1];
        }

        // combos per column: a=f0-.5f2, c=f0+.5f2, b=-.5(f1+f3), d=.5(f3-f1)
        const float ax = x0.x - 0.5f*x2.x, ay = x0.y - 0.5f*x2.y, az = x0.z - 0.5f*x2.z, aw = x0.w - 0.5f*x2.w;
        const float cx = x0.x + 0.5f*x2.x, cy = x0.y + 0.5f*x2.y, cz = x0.z + 0.5f*x2.z, cw = x0.w + 0.5f*x2.w;
        const float bx = -0.5f*(x1.x + x3.x), by = -0.5f*(x1.y + x3.y), bz = -0.5f*(x1.z + x3.z), bw = -0.5f*(x1.w + x3.w);
        const float dx =  0.5f*(x3.x - x1.x), dy =  0.5f*(x3.y - x1.y), dz =  0.5f*(x3.z - x1.z), dw =  0.5f*(x3.w - x1.w);

        const float g00x = ax + bx, g00y = ay + by, g00z = az + bz, g00w = aw + bw;
        const float g01x = ax - bx, g01y = ay - by, g01z = az - bz, g01w = aw - bw;
        const float g10x = cx + dx, g10y = cy + dy, g10z = cz + dz, g10w = cw + dw;
        const float g11x = cx - dx, g11y = cy - dy, g11z = cz - dz, g11w = cw - dw;

        // left-neighbor g01/g11 (zero for the j=0 boundary at t==0)
        const float la = l0 - 0.5f*l2, lb = -0.5f*(l1 + l3);
        const float lc = l0 + 0.5f*l2, ld =  0.5f*(l3 - l1);
        const float lg01 = la - lb;
        const float lg11 = lc - ld;

        const float Ux = g00x + lg01, Uy = g00y + g01x, Uz = g00z + g01y, Uw = g00w + g01z;
        const float Lx = g10x + lg11, Ly = g10y + g11x, Lz = g10z + g11y, Lw = g10w + g11z;

        if (r >= o0) {
            const float ici = (r == 0) ? 1.0f : 0.5f;   // row-count inverse (r<512 here)
            float* prow = po + r * OW + j0;
            prow[0] = (Ux + pLx) * (ici * cj0);
            prow[1] = (Uy + pLy) * (ici * 0.5f);
            prow[2] = (Uz + pLz) * (ici * 0.5f);
            prow[3] = (Uw + pLw) * (ici * 0.5f);
            if (t == 127) prow[4] = (g01w + pL512) * ici;   // col 512, cj=1
        }
        pLx = Lx; pLy = Ly; pLz = Lz; pLw = Lw;
        pL512 = g11w;
    }

    // last strip also owns output row 512 (= L[511] only, ci = 1)
    if (o0 + RSTRIP - 1 == HH) {
        float* prow = po + HH * OW + j0;
        prow[0] = pLx * cj0;
        prow[1] = pLy * 0.5f;
        prow[2] = pLz * 0.5f;
        prow[3] = pLw * 0.5f;
        if (t == 127) prow[4] = pL512;    // corner, count 1
    }
}

extern "C" void kernel_launch(void* const* d_in, const int* in_sizes, int n_in,
                              void* d_out, int out_size, void* d_ws, size_t ws_size,
                              hipStream_t stream) {
    const float* in0 = (const float*)d_in[0];
    const float* in1 = (const float*)d_in[1];
    const float* in2 = (const float*)d_in[2];
    const float* in3 = (const float*)d_in[3];
    float* out = (float*)d_out;

    dim3 grid(NSTRIP, 256);   // 19 row-strips x (B*C = 256) planes
    dim3 block(128);
    features2im_kernel<<<grid, block, 0, stream>>>(in0, in1, in2, in3, out);
}